// Round 13
// baseline (171.026 us; speedup 1.0000x reference)
//
#include <hip/hip_runtime.h>

#define NREAL 20000
#define MPAD  20096      // 314 * 64
#define HDIM  256
#define ODIM  128
#define NEDGE 320000
#define SCAN_B 20        // ceil(NREAL/1024)

typedef __attribute__((ext_vector_type(4))) float f32x4;
typedef __attribute__((ext_vector_type(2))) float f32x2;
typedef __attribute__((ext_vector_type(8))) short s16x8;
typedef __attribute__((ext_vector_type(4))) unsigned short u16x4;
typedef unsigned short u16;
typedef unsigned int u32;

__device__ inline u16 f2bf(float f) {
    u32 u = __float_as_uint(f);
    return (u16)((u + 0x7FFFu + ((u >> 16) & 1u)) >> 16);
}
__device__ inline float bf2f(u16 s) { return __uint_as_float(((u32)s) << 16); }

__device__ __forceinline__ void gload16(const void* g, void* l) {
    __builtin_amdgcn_global_load_lds((const __attribute__((address_space(1))) void*)g,
                                     (__attribute__((address_space(3))) void*)l, 16, 0, 0);
}

// ---------------- prep: pad-convert x, weight transpose/convert, degree count ----------------
__global__ __launch_bounds__(256) void k_prep(
    const float* __restrict__ x, u16* __restrict__ hbf,
    const float* __restrict__ wrel, const float* __restrict__ wroot,
    const float* __restrict__ wout,
    u16* __restrict__ brelT, u16* __restrict__ brootT, u16* __restrict__ boutT,
    const int* __restrict__ dst, int* __restrict__ deg)
{
    const int gt = blockIdx.x * 256 + threadIdx.x;
    const int gsz = gridDim.x * 256;
    for (long gid = gt; gid < (long)MPAD * HDIM / 4; gid += gsz) {
        long base = gid * 4;
        long row  = base >> 8;
        f32x4 v = {0.f, 0.f, 0.f, 0.f};
        if (row < NREAL) v = *(const f32x4*)(x + base);
        u16x4 hv;
        for (int j = 0; j < 4; ++j) hv[j] = f2bf(v[j]);
        *(u16x4*)(hbf + base) = hv;
    }
    for (int i = gt; i < 3 * 65536; i += gsz) {
        int l = i >> 16, r = i & 65535, n = r >> 8, k = r & 255;
        brelT[i]  = f2bf(wrel [l * 65536 + k * 256 + n]);
        brootT[i] = f2bf(wroot[l * 65536 + k * 256 + n]);
    }
    for (int i = gt; i < 128 * 256; i += gsz) {
        int n = i >> 8, k = i & 255;
        boutT[i] = f2bf(wout[k * 128 + n]);
    }
    for (int e = gt; e < NEDGE; e += gsz) atomicAdd(&deg[dst[e]], 1);
}

// ---------------- scan chain (blocksum -> fused small-scan + final scan) ----------------
__global__ __launch_bounds__(1024) void k_blocksum(const int* __restrict__ deg,
                                                   int* __restrict__ bsum) {
    __shared__ int red[16];
    int b = blockIdx.x, t = threadIdx.x;
    int i = b * 1024 + t;
    int v = (i < NREAL) ? deg[i] : 0;
    for (int off = 32; off; off >>= 1) v += __shfl_down(v, off);
    if ((t & 63) == 0) red[t >> 6] = v;
    __syncthreads();
    if (t < 16) {
        int s = red[t];
        for (int off = 8; off; off >>= 1) s += __shfl_down(s, off);
        if (t == 0) bsum[b] = s;
    }
}

__global__ __launch_bounds__(1024) void k_scanfinal(const int* __restrict__ deg,
                                                    const int* __restrict__ bsum,
                                                    int* __restrict__ rowptr,
                                                    int* __restrict__ cursor) {
    __shared__ int sm[1024];
    __shared__ int chunkoff;
    int b = blockIdx.x, t = threadIdx.x;
    // wave 0: redundant exclusive scan of the 20 chunk sums; lane b keeps ours
    if (t < 64) {
        int v = (t < SCAN_B) ? bsum[t] : 0;
        int orig = v;
        for (int off = 1; off < 64; off <<= 1) {
            int u = __shfl_up(v, off);
            if (t >= off) v += u;
        }
        if (t == b) chunkoff = v - orig;
    }
    int i = b * 1024 + t;
    int v = (i < NREAL) ? deg[i] : 0;
    sm[t] = v;
    __syncthreads();
    for (int off = 1; off < 1024; off <<= 1) {
        int u = (t >= off) ? sm[t - off] : 0;
        __syncthreads();
        if (t >= off) sm[t] += u;
        __syncthreads();
    }
    if (i < NREAL) {
        int excl = chunkoff + sm[t] - v;
        rowptr[i] = excl;
        cursor[i] = excl;
    }
    if (b == 0 && t == 0) rowptr[NREAL] = NEDGE;
}

// edge key: (attr_bf16 << 16) | src   (src < 2^16)
__global__ void k_fill(const int* __restrict__ src, const int* __restrict__ dst,
                       const float* __restrict__ attr, int* __restrict__ cursor,
                       u32* __restrict__ csr_edge) {
    int e = blockIdx.x * 256 + threadIdx.x;
    if (e < NEDGE) {
        int d = dst[e];
        int p = atomicAdd(&cursor[d], 1);
        csr_edge[p] = (((u32)f2bf(attr[e])) << 16) | (u32)src[e];
    }
}

// 8-deep pipelined gather-accumulate over one zero-padded 64-edge chunk.
__device__ __forceinline__ void agg_pairs(u32 ej, int npair, int half, int col8,
                                          const u16* __restrict__ hbf, f32x2 acc2[4]) {
    const int nbat = (npair + 7) >> 3;
    for (int bt = 0; bt < nbat; ++bt) {
        u32 ee[8];
        s16x8 v[8];
        #pragma unroll
        for (int b = 0; b < 8; ++b) {
            ee[b] = (u32)__shfl((int)ej, 2 * (bt * 8 + b) + half);   // <= 63
            v[b]  = *(const s16x8*)(hbf + ((long)(ee[b] & 0xffffu) << 8) + col8);
        }
        #pragma unroll
        for (int b = 0; b < 8; ++b) {
            float a = __uint_as_float(ee[b] & 0xffff0000u);
            f32x2 a2 = {a, a};
            const u32* vw = (const u32*)&v[b];
            #pragma unroll
            for (int k = 0; k < 4; ++k) {
                f32x2 hv = {__uint_as_float(vw[k] << 16),
                            __uint_as_float(vw[k] & 0xffff0000u)};
                acc2[k] += a2 * hv;
            }
        }
    }
}

// process one node: optional canonical in-register sort (layer 1), gather, reduce, store
template <bool SORT>
__device__ __forceinline__ void do_node(
    int node, int beg, int deg, u32 ejf,
    int lane, int half, int col8,
    const u16* __restrict__ hbf, u32* __restrict__ csr_edge,
    u16* __restrict__ agg)
{
    f32x2 acc2[4];
    #pragma unroll
    for (int k = 0; k < 4; ++k) { acc2[k][0] = 0.f; acc2[k][1] = 0.f; }

    if (node < NREAL) {
        if (deg >= 1 && deg <= 64) {
            u32 val = ejf;
            if (SORT) {
                if (deg > 1) {
                    #pragma unroll
                    for (int ph = 0; ph < 64; ++ph) {
                        int base = ph & 1;
                        int partner = lane + (((lane ^ base) & 1) ? -1 : +1);
                        if (partner < 0 || partner > 63) partner = lane;
                        u32 p = (u32)__shfl((int)val, partner);
                        if (partner != lane)
                            val = (lane < partner) ? (val < p ? val : p) : (val > p ? val : p);
                    }
                }
                if (lane < deg) csr_edge[beg + lane] = val;
                else            val = 0u;           // clamp sentinel lanes
            }
            agg_pairs(val, (deg + 1) >> 1, half, col8, hbf, acc2);
        } else if (deg > 64) {
            if (SORT) {
                if (lane == 0) {
                    for (int i = beg + 1; i < beg + deg; ++i) {
                        u32 key = csr_edge[i];
                        int j = i - 1;
                        while (j >= beg && csr_edge[j] > key) { csr_edge[j + 1] = csr_edge[j]; --j; }
                        csr_edge[j + 1] = key;
                    }
                }
                asm volatile("s_waitcnt vmcnt(0)" ::: "memory");  // lane0 stores -> wave loads
            }
            for (int c = beg; c < beg + deg; c += 64) {
                int m = beg + deg - c; if (m > 64) m = 64;
                u32 ejc = csr_edge[c + (lane < m ? lane : 0)];
                if (lane >= m) ejc = 0u;
                agg_pairs(ejc, (m + 1) >> 1, half, col8, hbf, acc2);
            }
        }
    }
    #pragma unroll
    for (int k = 0; k < 4; ++k) {
        acc2[k][0] += __shfl_xor(acc2[k][0], 32);
        acc2[k][1] += __shfl_xor(acc2[k][1], 32);
    }
    if (half == 0) {
        s16x8 hv;
        #pragma unroll
        for (int k = 0; k < 4; ++k) {
            hv[2 * k]     = (short)f2bf(acc2[k][0]);
            hv[2 * k + 1] = (short)f2bf(acc2[k][1]);
        }
        *(s16x8*)(agg + (long)node * HDIM + col8) = hv;   // pads/deg0 get zeros
    }
}

// ---------------- aggregation: 2 nodes per wave, meta prefetched for both ----------------
template <bool SORT>
__global__ __launch_bounds__(256) void k_aggregate(
    const u16* __restrict__ hbf, const int* __restrict__ rowptr,
    u32* __restrict__ csr_edge, u16* __restrict__ agg)
{
    const int lane = threadIdx.x & 63;
    const int half = lane >> 5;
    const int col8 = (lane & 31) * 8;
    const int n0 = blockIdx.x * 4 + (threadIdx.x >> 6);   // grid = MPAD/8
    const int n1 = n0 + MPAD / 2;

    int beg0 = 0, deg0 = 0, beg1 = 0, deg1 = 0;
    if (n0 < NREAL) { beg0 = rowptr[n0]; deg0 = rowptr[n0 + 1] - beg0; }
    if (n1 < NREAL) { beg1 = rowptr[n1]; deg1 = rowptr[n1 + 1] - beg1; }
    u32 ej0 = SORT ? 0xFFFFFFFFu : 0u;
    u32 ej1 = SORT ? 0xFFFFFFFFu : 0u;
    if (deg0 >= 1 && deg0 <= 64 && lane < deg0) ej0 = csr_edge[beg0 + lane];
    if (deg1 >= 1 && deg1 <= 64 && lane < deg1) ej1 = csr_edge[beg1 + lane];

    do_node<SORT>(n0, beg0, deg0, ej0, lane, half, col8, hbf, csr_edge, agg);
    do_node<SORT>(n1, beg1, deg1, ej1, lane, half, col8, hbf, csr_edge, agg);
}

// ---------------- GEMM: 64x128 tile, BK=64, gload_lds staging, swizzled LDS ----------------
// A bf16 [MPAD][256]; B pre-transposed bf16 [Nt][256].
// Row = 64 u16 = 8 slots of 16 B. LDS[row][slot] = G[row][slot ^ (row&7)]
// via pre-swizzled global source; reads XOR the same way.
__global__ __launch_bounds__(256) void k_gemm(
    const u16* __restrict__ A1, const u16* __restrict__ A2,
    const u16* __restrict__ BT1, const u16* __restrict__ BT2,
    const float* __restrict__ bias,
    u16* __restrict__ hout, float* __restrict__ final_out, int Nt)
{
    __shared__ __align__(16) u16 As[64 * 64];    // 8 KB
    __shared__ __align__(16) u16 Bs[128 * 64];   // 16 KB

    const int t    = threadIdx.x;
    const int bm   = blockIdx.x, bn = blockIdx.y;
    const int lane = t & 63;
    const int wave = t >> 6;
    const int wr   = (wave >> 1) * 32;   // 0 | 32
    const int wc   = (wave & 1) * 64;    // 0 | 64
    const int lrow = lane & 15;
    const int lks  = lane >> 4;          // k-slot group 0..3

    f32x4 acc[2][4];
    #pragma unroll
    for (int i = 0; i < 2; ++i)
        #pragma unroll
        for (int j = 0; j < 4; ++j)
            #pragma unroll
            for (int r = 0; r < 4; ++r) acc[i][j][r] = 0.f;

    const int lrow8 = lane >> 3;
    const int ssrc  = ((lane & 7) ^ lrow8) * 8;   // u16 offset within row

    const int nmat = A2 ? 2 : 1;
    for (int mat = 0; mat < nmat; ++mat) {
        const u16* A_g = mat ? A2  : A1;
        const u16* B_g = mat ? BT2 : BT1;
        for (int k0 = 0; k0 < HDIM; k0 += 64) {
            __syncthreads();
            #pragma unroll
            for (int i = 0; i < 2; ++i) {
                int ch  = wave * 2 + i;
                int row = ch * 8 + lrow8;
                gload16(A_g + (size_t)(bm * 64 + row) * HDIM + k0 + ssrc, &As[ch * 512]);
            }
            #pragma unroll
            for (int i = 0; i < 4; ++i) {
                int ch  = wave * 4 + i;
                int row = ch * 8 + lrow8;
                gload16(B_g + (size_t)(bn * 128 + row) * HDIM + k0 + ssrc, &Bs[ch * 512]);
            }
            __syncthreads();
            #pragma unroll
            for (int kk = 0; kk < 2; ++kk) {
                int slot = kk * 4 + lks;
                s16x8 bfr[4];
                #pragma unroll
                for (int nj = 0; nj < 4; ++nj) {
                    int r = wc + nj * 16 + lrow;
                    bfr[nj] = *(const s16x8*)&Bs[r * 64 + ((slot ^ (r & 7)) * 8)];
                }
                #pragma unroll
                for (int mi = 0; mi < 2; ++mi) {
                    int r = wr + mi * 16 + lrow;
                    s16x8 a = *(const s16x8*)&As[r * 64 + ((slot ^ (r & 7)) * 8)];
                    #pragma unroll
                    for (int nj = 0; nj < 4; ++nj)
                        acc[mi][nj] = __builtin_amdgcn_mfma_f32_16x16x32_bf16(a, bfr[nj], acc[mi][nj], 0, 0, 0);
                }
            }
        }
    }

    const int rb = (lane >> 4) * 4;
    #pragma unroll
    for (int mi = 0; mi < 2; ++mi) {
        #pragma unroll
        for (int nj = 0; nj < 4; ++nj) {
            int col = bn * 128 + wc + nj * 16 + lrow;
            float bsv = bias[col];
            #pragma unroll
            for (int r = 0; r < 4; ++r) {
                int row = bm * 64 + wr + mi * 16 + rb + r;
                float v = acc[mi][nj][r] + bsv;
                v = v > 0.f ? v : 0.f;
                if (final_out) {
                    if (row < NREAL) final_out[(long)row * Nt + col] = v;
                } else {
                    hout[(long)row * HDIM + col] = f2bf(v);
                }
            }
        }
    }
}

static inline char* align256(char* p) {
    return (char*)(((size_t)p + 255) & ~(size_t)255);
}

extern "C" void kernel_launch(void* const* d_in, const int* in_sizes, int n_in,
                              void* d_out, int out_size, void* d_ws, size_t ws_size,
                              hipStream_t stream) {
    const float* x     = (const float*)d_in[0];
    const int*   eidx  = (const int*)  d_in[1];
    const float* attr  = (const float*)d_in[2];
    const float* wrel  = (const float*)d_in[3];
    const float* brel  = (const float*)d_in[4];
    const float* wroot = (const float*)d_in[5];
    const float* wout  = (const float*)d_in[6];
    const float* bout  = (const float*)d_in[7];
    const int* src = eidx;
    const int* dst = eidx + NEDGE;

    char* ws = (char*)d_ws;
    u16* hbfA  = (u16*)ws;        ws = align256(ws + (size_t)MPAD * HDIM * 2);
    u16* hbfB  = (u16*)ws;        ws = align256(ws + (size_t)MPAD * HDIM * 2);
    u16* aggbf = (u16*)ws;        ws = align256(ws + (size_t)MPAD * HDIM * 2);
    u16* brelT  = (u16*)ws;       ws = align256(ws + (size_t)3 * 65536 * 2);
    u16* brootT = (u16*)ws;       ws = align256(ws + (size_t)3 * 65536 * 2);
    u16* boutT  = (u16*)ws;       ws = align256(ws + (size_t)128 * 256 * 2);
    int* deg    = (int*)ws;       ws = align256(ws + (size_t)NREAL * 4);
    int* rowptr = (int*)ws;       ws = align256(ws + (size_t)(NREAL + 1) * 4);
    int* cursor = (int*)ws;       ws = align256(ws + (size_t)NREAL * 4);
    int* bsum   = (int*)ws;       ws = align256(ws + (size_t)SCAN_B * 4);
    u32* csr_edge = (u32*)ws;     ws = align256(ws + (size_t)NEDGE * 4);

    hipMemsetAsync(deg, 0, (size_t)NREAL * 4, stream);
    k_prep<<<2048, 256, 0, stream>>>(x, hbfA, wrel, wroot, wout,
                                     brelT, brootT, boutT, dst, deg);
    k_blocksum<<<SCAN_B, 1024, 0, stream>>>(deg, bsum);
    k_scanfinal<<<SCAN_B, 1024, 0, stream>>>(deg, bsum, rowptr, cursor);
    k_fill<<<(NEDGE + 255) / 256, 256, 0, stream>>>(src, dst, attr, cursor, csr_edge);

    u16* h_c = hbfA;
    u16* h_n = hbfB;
    for (int l = 0; l < 3; ++l) {
        if (l == 0)
            k_aggregate<true><<<MPAD / 8, 256, 0, stream>>>(h_c, rowptr, csr_edge, aggbf);
        else
            k_aggregate<false><<<MPAD / 8, 256, 0, stream>>>(h_c, rowptr, csr_edge, aggbf);
        k_gemm<<<dim3(MPAD / 64, 2), 256, 0, stream>>>(
            aggbf, h_c,
            brelT + (size_t)l * 65536, brootT + (size_t)l * 65536,
            brel + (size_t)l * HDIM,
            h_n, nullptr, HDIM);
        u16* tp = h_c; h_c = h_n; h_n = tp;
    }
    k_gemm<<<dim3(MPAD / 64, 1), 256, 0, stream>>>(
        h_c, nullptr, boutT, nullptr, bout,
        nullptr, (float*)d_out, ODIM);
}